// Round 1
// baseline (627.403 us; speedup 1.0000x reference)
//
#include <hip/hip_runtime.h>

typedef __attribute__((ext_vector_type(4))) float f32x4;
typedef __attribute__((ext_vector_type(8))) short s16x8;

__device__ __forceinline__ float bf2f(short b) {
  unsigned int u = ((unsigned int)(unsigned short)b) << 16;
  return __builtin_bit_cast(float, u);
}
__device__ __forceinline__ short f2bf(float f) {
  unsigned int u = __builtin_bit_cast(unsigned int, f);
  u = (u + 0x7fffu + ((u >> 16) & 1u)) >> 16;
  return (short)u;
}

__device__ __forceinline__ void async_copy16(void* lds, const void* g) {
  __builtin_amdgcn_global_load_lds((const __attribute__((address_space(1))) unsigned int*)g,
                                   (__attribute__((address_space(3))) unsigned int*)lds,
                                   16, 0, 0);
}

// ---------------- pack kernels ----------------

__global__ __launch_bounds__(256) void cvt_f32_bf16(const float* __restrict__ src,
                                                    short* __restrict__ dst, int n) {
  const int i = (blockIdx.x * 256 + threadIdx.x) * 4;
  if (i >= n) return;
  const float4 v = *(const float4*)&src[i];
  short4 o;
  o.x = f2bf(v.x); o.y = f2bf(v.y); o.z = f2bf(v.z); o.w = f2bf(v.w);
  *(short4*)&dst[i] = o;
}

// src fp32 [R][C] -> dst bf16 [C][R]
__global__ __launch_bounds__(256) void transpose_cvt(const float* __restrict__ src,
                                                     short* __restrict__ dst, int R, int C) {
  __shared__ float t[32][33];
  const int c0 = blockIdx.x * 32, r0 = blockIdx.y * 32;
  const int tx = threadIdx.x & 31;
  const int ty = threadIdx.x >> 5;  // 0..7
#pragma unroll
  for (int i = 0; i < 4; ++i)
    t[ty + 8 * i][tx] = src[(size_t)(r0 + ty + 8 * i) * C + c0 + tx];
  __syncthreads();
#pragma unroll
  for (int i = 0; i < 4; ++i)
    dst[(size_t)(c0 + ty + 8 * i) * R + r0 + tx] = f2bf(t[tx][ty + 8 * i]);
}

// ---------------- GEMM: C[M][N] = A[M][K] * BT[N][K]^T ----------------

template <bool OUT_BF16>
__global__ __launch_bounds__(256) void gemm_bt(const short* __restrict__ A,
                                               const short* __restrict__ BT,
                                               void* __restrict__ Cout,
                                               int M, int N, int K) {
  __shared__ short As[128 * 32];
  __shared__ short Bs[128 * 32];
  const int tid = threadIdx.x;
  const int l = tid & 63, wid = tid >> 6;
  const int m0 = blockIdx.x * 128, n0 = blockIdx.y * 128;
  const int wr = (wid >> 1) * 64, wc = (wid & 1) * 64;
  const int lr = l & 15, lc = l >> 4;
  f32x4 acc[4][4] = {};

  for (int k0 = 0; k0 < K; k0 += 32) {
    __syncthreads();
#pragma unroll
    for (int i = 0; i < 2; ++i) {
      const int c = tid + 256 * i;
      const int row = c >> 2, kc = (c & 3) * 8;
      async_copy16((char*)As + (size_t)(i * 256 + wid * 64) * 16,
                   A + (size_t)(m0 + row) * K + k0 + kc);
      async_copy16((char*)Bs + (size_t)(i * 256 + wid * 64) * 16,
                   BT + (size_t)(n0 + row) * K + k0 + kc);
    }
    __syncthreads();
    s16x8 a[4], b[4];
#pragma unroll
    for (int m = 0; m < 4; ++m)
      a[m] = *(const s16x8*)&As[(wr + m * 16 + lr) * 32 + lc * 8];
#pragma unroll
    for (int n = 0; n < 4; ++n)
      b[n] = *(const s16x8*)&Bs[(wc + n * 16 + lr) * 32 + lc * 8];
#pragma unroll
    for (int m = 0; m < 4; ++m)
#pragma unroll
      for (int n = 0; n < 4; ++n)
        acc[m][n] = __builtin_amdgcn_mfma_f32_16x16x32_bf16(a[m], b[n], acc[m][n], 0, 0, 0);
  }

#pragma unroll
  for (int m = 0; m < 4; ++m)
#pragma unroll
    for (int n = 0; n < 4; ++n)
#pragma unroll
      for (int r = 0; r < 4; ++r) {
        const size_t row = (size_t)(m0 + wr + m * 16 + lc * 4 + r);
        const int col = n0 + wc + n * 16 + lr;
        if constexpr (OUT_BF16)
          ((short*)Cout)[row * N + col] = f2bf(acc[m][n][r]);
        else
          ((float*)Cout)[row * N + col] = acc[m][n][r];
      }
}

// ---------------- RoPE (in-place on qkv bf16 [4096][3072]) ----------------

__global__ __launch_bounds__(256) void rope_kernel(short* __restrict__ qkv,
                                                   const float* __restrict__ cosb,
                                                   const float* __restrict__ sinb) {
  const int idx = blockIdx.x * 256 + threadIdx.x;  // 4096*20*64 threads
  const int d = idx & 63;
  const int hh = (idx >> 6) % 20;
  const int row = idx / (64 * 20);
  const int lpos = row & 2047;
  const int col = (hh < 16) ? hh * 128 + d : 2048 + (hh - 16) * 128 + d;
  short* p = qkv + (size_t)row * 3072 + col;
  const float x1 = bf2f(p[0]);
  const float x2 = bf2f(p[64]);
  const float c = cosb[lpos * 128 + d];
  const float s = sinb[lpos * 128 + d];
  p[0]  = f2bf(x1 * c - x2 * s);
  p[64] = f2bf(x2 * c + x1 * s);
}

// ---------------- flash attention (causal, GQA 16/4, hd=128) ----------------

__global__ __launch_bounds__(256) void flash_attn(const short* __restrict__ qkv,
                                                  short* __restrict__ attn_out) {
  __shared__ short Ks[32 * 136];
  __shared__ short Vs[32 * 136];
  __shared__ short Pb[4][16 * 40];
  const int tid = threadIdx.x;
  const int l = tid & 63, w = tid >> 6;
  const int lr = l & 15, lc = l >> 4;
  const int qt = blockIdx.x, h = blockIdx.y, b = blockIdx.z;
  const int kvh = h >> 2;
  const short* Qg = qkv + (size_t)b * 2048 * 3072 + h * 128;
  const short* Kg = qkv + (size_t)b * 2048 * 3072 + 2048 + kvh * 128;
  const short* Vg = qkv + (size_t)b * 2048 * 3072 + 2560 + kvh * 128;
  const int qbase = qt * 64 + w * 16;

  s16x8 qf[4];
#pragma unroll
  for (int dc = 0; dc < 4; ++dc)
    qf[dc] = *(const s16x8*)&Qg[(size_t)(qbase + lr) * 3072 + dc * 32 + lc * 8];

  f32x4 oacc[8] = {};
  float mrow[4], ssum[4];
#pragma unroll
  for (int r = 0; r < 4; ++r) { mrow[r] = -__builtin_inff(); ssum[r] = 0.f; }
  const float scale = 0.08838834764831845f;
  const int nkt = qt * 2 + 2;

  for (int kt = 0; kt < nkt; ++kt) {
    const int kv0 = kt * 32;
    __syncthreads();
#pragma unroll
    for (int i = 0; i < 2; ++i) {
      const int c = tid + 256 * i;
      const int r = c >> 4, sl = (c & 15) * 8;
      *(s16x8*)&Ks[r * 136 + sl] = *(const s16x8*)&Kg[(size_t)(kv0 + r) * 3072 + sl];
      *(s16x8*)&Vs[r * 136 + sl] = *(const s16x8*)&Vg[(size_t)(kv0 + r) * 3072 + sl];
    }
    __syncthreads();
    if (kv0 > qbase + 15) continue;  // fully-masked for this wave (barrier counts stay uniform)

    f32x4 sacc[2] = {};
#pragma unroll
    for (int cb = 0; cb < 2; ++cb)
#pragma unroll
      for (int dc = 0; dc < 4; ++dc) {
        const s16x8 kf = *(const s16x8*)&Ks[(cb * 16 + lr) * 136 + dc * 32 + lc * 8];
        sacc[cb] = __builtin_amdgcn_mfma_f32_16x16x32_bf16(qf[dc], kf, sacc[cb], 0, 0, 0);
      }

    const bool need_mask = (kv0 + 31 > qbase);
#pragma unroll
    for (int r = 0; r < 4; ++r) {
      float s0 = sacc[0][r] * scale;
      float s1 = sacc[1][r] * scale;
      if (need_mask) {
        const int qrow = qbase + lc * 4 + r;
        if (kv0 + lr > qrow) s0 = -1e30f;
        if (kv0 + 16 + lr > qrow) s1 = -1e30f;
      }
      float rm = fmaxf(s0, s1);
      rm = fmaxf(rm, __shfl_xor(rm, 1, 64));
      rm = fmaxf(rm, __shfl_xor(rm, 2, 64));
      rm = fmaxf(rm, __shfl_xor(rm, 4, 64));
      rm = fmaxf(rm, __shfl_xor(rm, 8, 64));
      const float mnew = fmaxf(mrow[r], rm);
      const float resc = __expf(mrow[r] - mnew);
      mrow[r] = mnew;
      const float p0 = __expf(s0 - mnew);
      const float p1 = __expf(s1 - mnew);
      float rs = p0 + p1;
      rs += __shfl_xor(rs, 1, 64);
      rs += __shfl_xor(rs, 2, 64);
      rs += __shfl_xor(rs, 4, 64);
      rs += __shfl_xor(rs, 8, 64);
      ssum[r] = ssum[r] * resc + rs;
#pragma unroll
      for (int db = 0; db < 8; ++db) oacc[db][r] *= resc;
      Pb[w][(lc * 4 + r) * 40 + lr] = f2bf(p0);
      Pb[w][(lc * 4 + r) * 40 + 16 + lr] = f2bf(p1);
    }

    const s16x8 pf = *(const s16x8*)&Pb[w][lr * 40 + lc * 8];
#pragma unroll
    for (int db = 0; db < 8; ++db) {
      s16x8 vf;
#pragma unroll
      for (int j = 0; j < 8; ++j)
        vf[j] = Vs[(lc * 8 + j) * 136 + db * 16 + lr];
      oacc[db] = __builtin_amdgcn_mfma_f32_16x16x32_bf16(pf, vf, oacc[db], 0, 0, 0);
    }
  }

#pragma unroll
  for (int r = 0; r < 4; ++r) {
    const float inv = 1.0f / ssum[r];
    const size_t orow = (size_t)b * 2048 + qbase + lc * 4 + r;
#pragma unroll
    for (int db = 0; db < 8; ++db)
      attn_out[orow * 2048 + h * 128 + db * 16 + lr] = f2bf(oacc[db][r] * inv);
  }
}

// ---------------- launch ----------------

extern "C" void kernel_launch(void* const* d_in, const int* in_sizes, int n_in,
                              void* d_out, int out_size, void* d_ws, size_t ws_size,
                              hipStream_t stream) {
  const float* x    = (const float*)d_in[0];
  const float* cosb = (const float*)d_in[1];
  const float* sinb = (const float*)d_in[2];
  const float* wq   = (const float*)d_in[3];
  const float* wk   = (const float*)d_in[4];
  const float* wv   = (const float*)d_in[5];
  const float* wo   = (const float*)d_in[6];
  float* out = (float*)d_out;

  char* ws = (char*)d_ws;
  short* xb    = (short*)(ws);                 // [4096][2048] bf16
  short* wqkvT = (short*)(ws + 16777216);      // [3072][2048] bf16 (q|k|v cols, transposed)
  short* woT   = (short*)(ws + 29360128);      // [2048][2048] bf16 transposed
  short* qkvb  = (short*)(ws + 37748736);      // [4096][3072] bf16
  short* attnb = (short*)(ws + 62914560);      // [4096][2048] bf16

  cvt_f32_bf16<<<8192, 256, 0, stream>>>(x, xb, 8388608);
  transpose_cvt<<<dim3(64, 64), 256, 0, stream>>>(wq, wqkvT, 2048, 2048);
  transpose_cvt<<<dim3(16, 64), 256, 0, stream>>>(wk, wqkvT + 2048 * 2048, 2048, 512);
  transpose_cvt<<<dim3(16, 64), 256, 0, stream>>>(wv, wqkvT + 2560 * 2048, 2048, 512);
  transpose_cvt<<<dim3(64, 64), 256, 0, stream>>>(wo, woT, 2048, 2048);

  gemm_bt<true><<<dim3(32, 24), 256, 0, stream>>>(xb, wqkvT, qkvb, 4096, 3072, 2048);
  rope_kernel<<<20480, 256, 0, stream>>>(qkvb, cosb, sinb);
  flash_attn<<<dim3(32, 16, 2), 256, 0, stream>>>(qkvb, attnb);
  gemm_bt<false><<<dim3(32, 16), 256, 0, stream>>>(attnb, woT, out, 4096, 2048, 2048);
}

// Round 2
// 427.128 us; speedup vs baseline: 1.4689x; 1.4689x over previous
//
#include <hip/hip_runtime.h>

typedef __attribute__((ext_vector_type(4))) float f32x4;
typedef __attribute__((ext_vector_type(8))) short s16x8;

__device__ __forceinline__ float bf2f(short b) {
  unsigned int u = ((unsigned int)(unsigned short)b) << 16;
  return __builtin_bit_cast(float, u);
}
__device__ __forceinline__ short f2bf(float f) {
  unsigned int u = __builtin_bit_cast(unsigned int, f);
  u = (u + 0x7fffu + ((u >> 16) & 1u)) >> 16;
  return (short)u;
}

__device__ __forceinline__ void async_copy16(void* lds, const void* g) {
  __builtin_amdgcn_global_load_lds((const __attribute__((address_space(1))) unsigned int*)g,
                                   (__attribute__((address_space(3))) unsigned int*)lds,
                                   16, 0, 0);
}

// ---------------- pack kernels ----------------

__global__ __launch_bounds__(256) void cvt_f32_bf16(const float* __restrict__ src,
                                                    short* __restrict__ dst, int n) {
  const int i = (blockIdx.x * 256 + threadIdx.x) * 4;
  if (i >= n) return;
  const float4 v = *(const float4*)&src[i];
  short4 o;
  o.x = f2bf(v.x); o.y = f2bf(v.y); o.z = f2bf(v.z); o.w = f2bf(v.w);
  *(short4*)&dst[i] = o;
}

// src fp32 [R][C] -> dst bf16 [C][R]
__global__ __launch_bounds__(256) void transpose_cvt(const float* __restrict__ src,
                                                     short* __restrict__ dst, int R, int C) {
  __shared__ float t[32][33];
  const int c0 = blockIdx.x * 32, r0 = blockIdx.y * 32;
  const int tx = threadIdx.x & 31;
  const int ty = threadIdx.x >> 5;  // 0..7
#pragma unroll
  for (int i = 0; i < 4; ++i)
    t[ty + 8 * i][tx] = src[(size_t)(r0 + ty + 8 * i) * C + c0 + tx];
  __syncthreads();
#pragma unroll
  for (int i = 0; i < 4; ++i)
    dst[(size_t)(c0 + ty + 8 * i) * R + r0 + tx] = f2bf(t[tx][ty + 8 * i]);
}

// bf16 V slice of qkv [B*2048][3072] -> vt [B][512][2048] (col-major per (b))
__global__ __launch_bounds__(256) void transpose_v(const short* __restrict__ qkv,
                                                   short* __restrict__ vt) {
  __shared__ short t[32][33];
  const int l0 = blockIdx.x * 32;  // L tile
  const int c0 = blockIdx.y * 32;  // col within 512
  const int b = blockIdx.z;
  const int tx = threadIdx.x & 31, ty = threadIdx.x >> 5;
#pragma unroll
  for (int i = 0; i < 4; ++i)
    t[ty + 8 * i][tx] = qkv[(size_t)(b * 2048 + l0 + ty + 8 * i) * 3072 + 2560 + c0 + tx];
  __syncthreads();
#pragma unroll
  for (int i = 0; i < 4; ++i)
    vt[((size_t)b * 512 + c0 + ty + 8 * i) * 2048 + l0 + tx] = t[tx][ty + 8 * i];
}

// ---------------- GEMM: C[M][N] = A[M][K] * BT[N][K]^T ----------------

template <bool OUT_BF16>
__global__ __launch_bounds__(256) void gemm_bt(const short* __restrict__ A,
                                               const short* __restrict__ BT,
                                               void* __restrict__ Cout,
                                               int M, int N, int K) {
  __shared__ short As[128 * 32];
  __shared__ short Bs[128 * 32];
  const int tid = threadIdx.x;
  const int l = tid & 63, wid = tid >> 6;
  const int m0 = blockIdx.x * 128, n0 = blockIdx.y * 128;
  const int wr = (wid >> 1) * 64, wc = (wid & 1) * 64;
  const int lr = l & 15, lc = l >> 4;
  f32x4 acc[4][4] = {};

  for (int k0 = 0; k0 < K; k0 += 32) {
    __syncthreads();
#pragma unroll
    for (int i = 0; i < 2; ++i) {
      const int c = tid + 256 * i;
      const int row = c >> 2, kc = (c & 3) * 8;
      async_copy16((char*)As + (size_t)(i * 256 + wid * 64) * 16,
                   A + (size_t)(m0 + row) * K + k0 + kc);
      async_copy16((char*)Bs + (size_t)(i * 256 + wid * 64) * 16,
                   BT + (size_t)(n0 + row) * K + k0 + kc);
    }
    __syncthreads();
    s16x8 a[4], b[4];
#pragma unroll
    for (int m = 0; m < 4; ++m)
      a[m] = *(const s16x8*)&As[(wr + m * 16 + lr) * 32 + lc * 8];
#pragma unroll
    for (int n = 0; n < 4; ++n)
      b[n] = *(const s16x8*)&Bs[(wc + n * 16 + lr) * 32 + lc * 8];
#pragma unroll
    for (int m = 0; m < 4; ++m)
#pragma unroll
      for (int n = 0; n < 4; ++n)
        acc[m][n] = __builtin_amdgcn_mfma_f32_16x16x32_bf16(a[m], b[n], acc[m][n], 0, 0, 0);
  }

#pragma unroll
  for (int m = 0; m < 4; ++m)
#pragma unroll
    for (int n = 0; n < 4; ++n)
#pragma unroll
      for (int r = 0; r < 4; ++r) {
        const size_t row = (size_t)(m0 + wr + m * 16 + lc * 4 + r);
        const int col = n0 + wc + n * 16 + lr;
        if constexpr (OUT_BF16)
          ((short*)Cout)[row * N + col] = f2bf(acc[m][n][r]);
        else
          ((float*)Cout)[row * N + col] = acc[m][n][r];
      }
}

// ---------------- RoPE (in-place on qkv bf16 [4096][3072]) ----------------

__global__ __launch_bounds__(256) void rope_kernel(short* __restrict__ qkv,
                                                   const float* __restrict__ cosb,
                                                   const float* __restrict__ sinb) {
  const int idx = blockIdx.x * 256 + threadIdx.x;  // 4096*20*64 threads
  const int d = idx & 63;
  const int hh = (idx >> 6) % 20;
  const int row = idx / (64 * 20);
  const int lpos = row & 2047;
  const int col = (hh < 16) ? hh * 128 + d : 2048 + (hh - 16) * 128 + d;
  short* p = qkv + (size_t)row * 3072 + col;
  const float x1 = bf2f(p[0]);
  const float x2 = bf2f(p[64]);
  const float c = cosb[lpos * 128 + d];
  const float s = sinb[lpos * 128 + d];
  p[0]  = f2bf(x1 * c - x2 * s);
  p[64] = f2bf(x2 * c + x1 * s);
}

// ---------------- flash attention (causal, GQA 16/4, hd=128) ----------------
// Block = 2 paired q-tiles (qt, 31-qt) of 64 rows each -> 33 KV tiles/block, uniform.
// 4 waves x 16 q-rows. KV tile = 64. K row-major padded; V transposed + XOR-swizzled.

__global__ __launch_bounds__(256) void flash_attn(const short* __restrict__ qkv,
                                                  const short* __restrict__ vt,
                                                  short* __restrict__ attn_out) {
  __shared__ short Ks[64 * 136];       // [kv=64][d=128], pad 136
  __shared__ short Vs[128 * 64];       // [d=128][kv=64], XOR-swizzled (^((d&7)<<3) on short idx)
  __shared__ short Pb[4][16 * 72];     // per-wave P [16 q][64 kv], pad 72
  const int tid = threadIdx.x;
  const int l = tid & 63, w = tid >> 6;
  const int lr = l & 15, lc = l >> 4;
  const int qpair = blockIdx.x, h = blockIdx.y, b = blockIdx.z;
  const int kvh = h >> 2;
  const short* Qg = qkv + (size_t)b * 2048 * 3072 + h * 128;
  const short* Kg = qkv + (size_t)b * 2048 * 3072 + 2048 + kvh * 128;
  const short* Vtg = vt + ((size_t)b * 512 + kvh * 128) * 2048;
  const float scale = 0.08838834764831845f;

#pragma unroll 1
  for (int seg = 0; seg < 2; ++seg) {
    const int qt = seg ? (31 - qpair) : qpair;
    const int qbase = qt * 64 + w * 16;

    s16x8 qf[4];
#pragma unroll
    for (int dc = 0; dc < 4; ++dc)
      qf[dc] = *(const s16x8*)&Qg[(size_t)(qbase + lr) * 3072 + dc * 32 + lc * 8];

    f32x4 oacc[8] = {};
    float mrow[4], ssum[4];
#pragma unroll
    for (int r = 0; r < 4; ++r) { mrow[r] = -__builtin_inff(); ssum[r] = 0.f; }
    const int nkt = qt + 1;

    for (int kt = 0; kt < nkt; ++kt) {
      const int kv0 = kt * 64;
      __syncthreads();
      // stage K: 64 rows x 128 elems (16 chunks of 8)
#pragma unroll
      for (int i = 0; i < 4; ++i) {
        const int c = tid + 256 * i;
        const int r = c >> 4, sl = (c & 15) * 8;
        *(s16x8*)&Ks[r * 136 + sl] = *(const s16x8*)&Kg[(size_t)(kv0 + r) * 3072 + sl];
      }
      // stage V transposed: 128 rows x 64 elems, 8-lane groups cover one row (128B)
#pragma unroll
      for (int p = 0; p < 4; ++p) {
        const int d = p * 32 + (tid >> 3);
        const int ch = tid & 7;
        *(s16x8*)&Vs[(d * 64 + ch * 8) ^ ((d & 7) << 3)] =
            *(const s16x8*)&Vtg[(size_t)d * 2048 + kv0 + ch * 8];
      }
      __syncthreads();

      // QK^T: S[16 q][64 kv]
      f32x4 sacc[4] = {};
      __builtin_amdgcn_s_setprio(1);
#pragma unroll
      for (int cb = 0; cb < 4; ++cb)
#pragma unroll
        for (int dc = 0; dc < 4; ++dc) {
          const s16x8 kf = *(const s16x8*)&Ks[(cb * 16 + lr) * 136 + dc * 32 + lc * 8];
          sacc[cb] = __builtin_amdgcn_mfma_f32_16x16x32_bf16(qf[dc], kf, sacc[cb], 0, 0, 0);
        }
      __builtin_amdgcn_s_setprio(0);

      const bool need_mask = (kv0 + 63 > qbase);
#pragma unroll
      for (int r = 0; r < 4; ++r) {
        float s0 = sacc[0][r] * scale;
        float s1 = sacc[1][r] * scale;
        float s2 = sacc[2][r] * scale;
        float s3 = sacc[3][r] * scale;
        if (need_mask) {
          const int qrow = qbase + lc * 4 + r;
          if (kv0 + lr > qrow) s0 = -1e30f;
          if (kv0 + 16 + lr > qrow) s1 = -1e30f;
          if (kv0 + 32 + lr > qrow) s2 = -1e30f;
          if (kv0 + 48 + lr > qrow) s3 = -1e30f;
        }
        float rm = fmaxf(fmaxf(s0, s1), fmaxf(s2, s3));
        rm = fmaxf(rm, __shfl_xor(rm, 1, 64));
        rm = fmaxf(rm, __shfl_xor(rm, 2, 64));
        rm = fmaxf(rm, __shfl_xor(rm, 4, 64));
        rm = fmaxf(rm, __shfl_xor(rm, 8, 64));
        const float mnew = fmaxf(mrow[r], rm);
        const float resc = __expf(mrow[r] - mnew);
        mrow[r] = mnew;
        const float p0 = __expf(s0 - mnew);
        const float p1 = __expf(s1 - mnew);
        const float p2 = __expf(s2 - mnew);
        const float p3 = __expf(s3 - mnew);
        float rs = (p0 + p1) + (p2 + p3);
        rs += __shfl_xor(rs, 1, 64);
        rs += __shfl_xor(rs, 2, 64);
        rs += __shfl_xor(rs, 4, 64);
        rs += __shfl_xor(rs, 8, 64);
        ssum[r] = ssum[r] * resc + rs;
#pragma unroll
        for (int db = 0; db < 8; ++db) oacc[db][r] *= resc;
        Pb[w][(lc * 4 + r) * 72 + lr]      = f2bf(p0);
        Pb[w][(lc * 4 + r) * 72 + 16 + lr] = f2bf(p1);
        Pb[w][(lc * 4 + r) * 72 + 32 + lr] = f2bf(p2);
        Pb[w][(lc * 4 + r) * 72 + 48 + lr] = f2bf(p3);
      }

      // PV: O += P[16][64] * V[64][128]
      __builtin_amdgcn_s_setprio(1);
#pragma unroll
      for (int kk = 0; kk < 2; ++kk) {
        const s16x8 pf = *(const s16x8*)&Pb[w][lr * 72 + kk * 32 + lc * 8];
#pragma unroll
        for (int db = 0; db < 8; ++db) {
          const s16x8 vf =
              *(const s16x8*)&Vs[((db * 16 + lr) * 64 + kk * 32 + lc * 8) ^ ((lr & 7) << 3)];
          oacc[db] = __builtin_amdgcn_mfma_f32_16x16x32_bf16(pf, vf, oacc[db], 0, 0, 0);
        }
      }
      __builtin_amdgcn_s_setprio(0);
    }

#pragma unroll
    for (int r = 0; r < 4; ++r) {
      const float inv = 1.0f / ssum[r];
      const size_t orow = (size_t)b * 2048 + qbase + lc * 4 + r;
#pragma unroll
      for (int db = 0; db < 8; ++db)
        attn_out[orow * 2048 + h * 128 + db * 16 + lr] = f2bf(oacc[db][r] * inv);
    }
  }
}

// ---------------- launch ----------------

extern "C" void kernel_launch(void* const* d_in, const int* in_sizes, int n_in,
                              void* d_out, int out_size, void* d_ws, size_t ws_size,
                              hipStream_t stream) {
  const float* x    = (const float*)d_in[0];
  const float* cosb = (const float*)d_in[1];
  const float* sinb = (const float*)d_in[2];
  const float* wq   = (const float*)d_in[3];
  const float* wk   = (const float*)d_in[4];
  const float* wv   = (const float*)d_in[5];
  const float* wo   = (const float*)d_in[6];
  float* out = (float*)d_out;

  char* ws = (char*)d_ws;
  short* xb    = (short*)(ws);                 // [4096][2048] bf16 (dead after gemm1)
  short* vtb   = (short*)(ws);                 // reuse xb region: [2][512][2048] bf16
  short* wqkvT = (short*)(ws + 16777216);      // [3072][2048] bf16 (q|k|v cols, transposed)
  short* woT   = (short*)(ws + 29360128);      // [2048][2048] bf16 transposed
  short* qkvb  = (short*)(ws + 37748736);      // [4096][3072] bf16
  short* attnb = (short*)(ws + 62914560);      // [4096][2048] bf16

  cvt_f32_bf16<<<8192, 256, 0, stream>>>(x, xb, 8388608);
  transpose_cvt<<<dim3(64, 64), 256, 0, stream>>>(wq, wqkvT, 2048, 2048);
  transpose_cvt<<<dim3(16, 64), 256, 0, stream>>>(wk, wqkvT + 2048 * 2048, 2048, 512);
  transpose_cvt<<<dim3(16, 64), 256, 0, stream>>>(wv, wqkvT + 2560 * 2048, 2048, 512);
  transpose_cvt<<<dim3(64, 64), 256, 0, stream>>>(wo, woT, 2048, 2048);

  gemm_bt<true><<<dim3(32, 24), 256, 0, stream>>>(xb, wqkvT, qkvb, 4096, 3072, 2048);
  rope_kernel<<<20480, 256, 0, stream>>>(qkvb, cosb, sinb);
  transpose_v<<<dim3(64, 16, 2), 256, 0, stream>>>(qkvb, vtb);
  flash_attn<<<dim3(16, 16, 2), 256, 0, stream>>>(qkvb, vtb, attnb);
  gemm_bt<false><<<dim3(32, 16), 256, 0, stream>>>(attnb, woT, out, 4096, 2048, 2048);
}

// Round 5
// 368.339 us; speedup vs baseline: 1.7033x; 1.1596x over previous
//
#include <hip/hip_runtime.h>

typedef __attribute__((ext_vector_type(4))) float f32x4;
typedef __attribute__((ext_vector_type(8))) short s16x8;

__device__ __forceinline__ float bf2f(short b) {
  unsigned int u = ((unsigned int)(unsigned short)b) << 16;
  return __builtin_bit_cast(float, u);
}
__device__ __forceinline__ short f2bf(float f) {
  unsigned int u = __builtin_bit_cast(unsigned int, f);
  u = (u + 0x7fffu + ((u >> 16) & 1u)) >> 16;
  return (short)u;
}

__device__ __forceinline__ void async_copy16(void* lds, const void* g) {
  __builtin_amdgcn_global_load_lds((const __attribute__((address_space(1))) unsigned int*)g,
                                   (__attribute__((address_space(3))) unsigned int*)lds,
                                   16, 0, 0);
}

// ---------------- pack kernels ----------------

__global__ __launch_bounds__(256) void cvt_f32_bf16(const float* __restrict__ src,
                                                    short* __restrict__ dst, int n) {
  const int i = (blockIdx.x * 256 + threadIdx.x) * 4;
  if (i >= n) return;
  const float4 v = *(const float4*)&src[i];
  short4 o;
  o.x = f2bf(v.x); o.y = f2bf(v.y); o.z = f2bf(v.z); o.w = f2bf(v.w);
  *(short4*)&dst[i] = o;
}

// src fp32 [R][C] -> dst bf16 [C][R]
__global__ __launch_bounds__(256) void transpose_cvt(const float* __restrict__ src,
                                                     short* __restrict__ dst, int R, int C) {
  __shared__ float t[32][33];
  const int c0 = blockIdx.x * 32, r0 = blockIdx.y * 32;
  const int tx = threadIdx.x & 31;
  const int ty = threadIdx.x >> 5;  // 0..7
#pragma unroll
  for (int i = 0; i < 4; ++i)
    t[ty + 8 * i][tx] = src[(size_t)(r0 + ty + 8 * i) * C + c0 + tx];
  __syncthreads();
#pragma unroll
  for (int i = 0; i < 4; ++i)
    dst[(size_t)(c0 + ty + 8 * i) * R + r0 + tx] = f2bf(t[tx][ty + 8 * i]);
}

// bf16 V slice of qkv [B*2048][3072] -> vt [B][512][2048], kv-permuted within each
// 64-block (kv' = (kv&15)*4 + (kv>>4)) and XOR-swizzled by d (^((d&7)<<3)).
__global__ __launch_bounds__(256) void transpose_v(const short* __restrict__ qkv,
                                                   short* __restrict__ vt) {
  __shared__ short t[32][33];
  const int l0 = blockIdx.x * 32;  // L tile
  const int c0 = blockIdx.y * 32;  // col within 512
  const int b = blockIdx.z;
  const int tx = threadIdx.x & 31, ty = threadIdx.x >> 5;
#pragma unroll
  for (int i = 0; i < 4; ++i)
    t[ty + 8 * i][tx] = qkv[(size_t)(b * 2048 + l0 + ty + 8 * i) * 3072 + 2560 + c0 + tx];
  __syncthreads();
#pragma unroll
  for (int i = 0; i < 4; ++i) {
    const int c = c0 + ty + 8 * i;     // d within 512 (head-aligned: d&127, swz uses d&7)
    const int l = l0 + tx;
    const int kv = l & 63;
    const int kvp = (((kv & 15) * 4 + (kv >> 4)) ^ ((c & 7) << 3));
    vt[((size_t)b * 512 + c) * 2048 + (l & ~63) + kvp] = t[tx][ty + 8 * i];
  }
}

// ---------------- GEMM: C[M][N] = A[M][K] * BT[N][K]^T ----------------

template <bool OUT_BF16>
__global__ __launch_bounds__(256) void gemm_bt(const short* __restrict__ A,
                                               const short* __restrict__ BT,
                                               void* __restrict__ Cout,
                                               int M, int N, int K) {
  __shared__ short As[128 * 32];
  __shared__ short Bs[128 * 32];
  const int tid = threadIdx.x;
  const int l = tid & 63, wid = tid >> 6;
  const int m0 = blockIdx.x * 128, n0 = blockIdx.y * 128;
  const int wr = (wid >> 1) * 64, wc = (wid & 1) * 64;
  const int lr = l & 15, lc = l >> 4;
  f32x4 acc[4][4] = {};

  for (int k0 = 0; k0 < K; k0 += 32) {
    __syncthreads();
#pragma unroll
    for (int i = 0; i < 2; ++i) {
      const int c = tid + 256 * i;
      const int row = c >> 2, kc = (c & 3) * 8;
      async_copy16((char*)As + (size_t)(i * 256 + wid * 64) * 16,
                   A + (size_t)(m0 + row) * K + k0 + kc);
      async_copy16((char*)Bs + (size_t)(i * 256 + wid * 64) * 16,
                   BT + (size_t)(n0 + row) * K + k0 + kc);
    }
    __syncthreads();
    s16x8 a[4], b[4];
#pragma unroll
    for (int m = 0; m < 4; ++m)
      a[m] = *(const s16x8*)&As[(wr + m * 16 + lr) * 32 + lc * 8];
#pragma unroll
    for (int n = 0; n < 4; ++n)
      b[n] = *(const s16x8*)&Bs[(wc + n * 16 + lr) * 32 + lc * 8];
#pragma unroll
    for (int m = 0; m < 4; ++m)
#pragma unroll
      for (int n = 0; n < 4; ++n)
        acc[m][n] = __builtin_amdgcn_mfma_f32_16x16x32_bf16(a[m], b[n], acc[m][n], 0, 0, 0);
  }

#pragma unroll
  for (int m = 0; m < 4; ++m)
#pragma unroll
    for (int n = 0; n < 4; ++n)
#pragma unroll
      for (int r = 0; r < 4; ++r) {
        const size_t row = (size_t)(m0 + wr + m * 16 + lc * 4 + r);
        const int col = n0 + wc + n * 16 + lr;
        if constexpr (OUT_BF16)
          ((short*)Cout)[row * N + col] = f2bf(acc[m][n][r]);
        else
          ((float*)Cout)[row * N + col] = acc[m][n][r];
      }
}

// ---------------- RoPE ----------------
// Q: in-place on qkv [4096][3072]. K: written to kswz [B][4][2048][128] with
// d-index XOR-swizzled (^((l&7)<<3)) so flash_attn can global_load_lds it linearly.

__global__ __launch_bounds__(256) void rope_kernel(short* __restrict__ qkv,
                                                   short* __restrict__ kswz,
                                                   const float* __restrict__ cosb,
                                                   const float* __restrict__ sinb) {
  const int idx = blockIdx.x * 256 + threadIdx.x;  // 4096*20*64 threads
  const int d = idx & 63;
  const int hh = (idx >> 6) % 20;
  const int row = idx / (64 * 20);
  const int lpos = row & 2047;
  const int col = (hh < 16) ? hh * 128 + d : 2048 + (hh - 16) * 128 + d;
  short* p = qkv + (size_t)row * 3072 + col;
  const float x1 = bf2f(p[0]);
  const float x2 = bf2f(p[64]);
  const float c = cosb[lpos * 128 + d];
  const float sn = sinb[lpos * 128 + d];
  const short o1 = f2bf(x1 * c - x2 * sn);
  const short o2 = f2bf(x2 * c + x1 * sn);
  if (hh < 16) {
    p[0] = o1;
    p[64] = o2;
  } else {
    const int b = row >> 11;
    const int kvh = hh - 16;
    short* kp = kswz + (((size_t)(b * 4 + kvh) * 2048) + lpos) * 128;
    const int sw = (lpos & 7) << 3;
    kp[d ^ sw] = o1;
    kp[(d + 64) ^ sw] = o2;
  }
}

// ---------------- flash attention (causal, GQA 16/4, hd=128) ----------------
// Block = 2 paired q-tiles (qt, 31-qt) of 64 rows -> 33 KV tiles/block, uniform.
// 4 waves x 16 q-rows. KV tile = 64. K/V staged via global_load_lds from
// pre-swizzled buffers; logits in base-2 (Q pre-scaled by scale*log2e);
// defer-max rescale (THR=8); P written as one ds_write_b64 per row.

__global__ __launch_bounds__(256) void flash_attn(const short* __restrict__ qkv,
                                                  const short* __restrict__ kswz,
                                                  const short* __restrict__ vt,
                                                  short* __restrict__ attn_out) {
  __shared__ short Ks[64 * 128];   // [kv][d^((kv&7)<<3)]
  __shared__ short Vs[128 * 64];   // [d][kv'^((d&7)<<3)]
  __shared__ short Pb[4][16 * 72]; // per-wave P [16 q][64 kv'], pad 72
  const int tid = threadIdx.x;
  const int l = tid & 63, w = tid >> 6;
  const int lr = l & 15, lc = l >> 4;
  const int sw = (lr & 7) << 3;
  const int qpair = blockIdx.x, h = blockIdx.y, b = blockIdx.z;
  const int kvh = h >> 2;
  const short* Qg = qkv + (size_t)b * 2048 * 3072 + h * 128;
  const short* Kg = kswz + ((size_t)(b * 4 + kvh) * 2048) * 128;
  const short* Vtg = vt + ((size_t)b * 512 + kvh * 128) * 2048;
  const float SCALE2 = 0.12751744166306968f;  // hd^-0.5 * log2(e)

#pragma unroll 1
  for (int seg = 0; seg < 2; ++seg) {
    const int qt = seg ? (31 - qpair) : qpair;
    const int qbase = qt * 64 + w * 16;

    s16x8 qf[4];
#pragma unroll
    for (int dc = 0; dc < 4; ++dc) {
      qf[dc] = *(const s16x8*)&Qg[(size_t)(qbase + lr) * 3072 + dc * 32 + lc * 8];
#pragma unroll
      for (int j = 0; j < 8; ++j) qf[dc][j] = f2bf(bf2f(qf[dc][j]) * SCALE2);
    }

    f32x4 oacc[8] = {};
    float mrow[4], ssum[4];
#pragma unroll
    for (int r = 0; r < 4; ++r) { mrow[r] = -__builtin_inff(); ssum[r] = 0.f; }
    const int nkt = qt + 1;

    for (int kt = 0; kt < nkt; ++kt) {
      const int kv0 = kt * 64;
      __syncthreads();
      // stage K (16KB) + V (16KB) via async global->LDS, linear dest
#pragma unroll
      for (int i = 0; i < 4; ++i) {
        async_copy16((char*)Ks + i * 4096 + w * 1024,
                     Kg + (size_t)kv0 * 128 + i * 2048 + w * 512 + l * 8);
        async_copy16((char*)Vs + i * 4096 + w * 1024,
                     Vtg + (size_t)(i * 32 + w * 8 + (l >> 3)) * 2048 + kv0 + (l & 7) * 8);
      }
      __syncthreads();

      // QK^T: S[16 q][64 kv] (base-2 logits)
      f32x4 sacc[4] = {};
      __builtin_amdgcn_s_setprio(1);
#pragma unroll
      for (int cb = 0; cb < 4; ++cb)
#pragma unroll
        for (int dc = 0; dc < 4; ++dc) {
          const s16x8 kf = *(const s16x8*)&Ks[(cb * 16 + lr) * 128 + ((dc * 32 + lc * 8) ^ sw)];
          sacc[cb] = __builtin_amdgcn_mfma_f32_16x16x32_bf16(qf[dc], kf, sacc[cb], 0, 0, 0);
        }
      __builtin_amdgcn_s_setprio(0);

      const bool need_mask = (kt == qt);
#pragma unroll
      for (int r = 0; r < 4; ++r) {
        float s0 = sacc[0][r];
        float s1 = sacc[1][r];
        float s2 = sacc[2][r];
        float s3 = sacc[3][r];
        if (need_mask) {
          const int qrow = qbase + lc * 4 + r;
          if (kv0 + lr > qrow) s0 = -1e30f;
          if (kv0 + 16 + lr > qrow) s1 = -1e30f;
          if (kv0 + 32 + lr > qrow) s2 = -1e30f;
          if (kv0 + 48 + lr > qrow) s3 = -1e30f;
        }
        float rm = fmaxf(fmaxf(s0, s1), fmaxf(s2, s3));
        rm = fmaxf(rm, __shfl_xor(rm, 1, 64));
        rm = fmaxf(rm, __shfl_xor(rm, 2, 64));
        rm = fmaxf(rm, __shfl_xor(rm, 4, 64));
        rm = fmaxf(rm, __shfl_xor(rm, 8, 64));
        if (!__all(rm <= mrow[r] + 8.f)) {
          const float mnew = fmaxf(mrow[r], rm);
          const float resc = exp2f(mrow[r] - mnew);
          mrow[r] = mnew;
          ssum[r] *= resc;
#pragma unroll
          for (int db = 0; db < 8; ++db) oacc[db][r] *= resc;
        }
        const float m = mrow[r];
        const float p0 = exp2f(s0 - m);
        const float p1 = exp2f(s1 - m);
        const float p2 = exp2f(s2 - m);
        const float p3 = exp2f(s3 - m);
        float rs = (p0 + p1) + (p2 + p3);
        rs += __shfl_xor(rs, 1, 64);
        rs += __shfl_xor(rs, 2, 64);
        rs += __shfl_xor(rs, 4, 64);
        rs += __shfl_xor(rs, 8, 64);
        ssum[r] += rs;
        // kv' = lr*4 + cb  ->  one b64 write per row
        uint2 u;
        u.x = (unsigned)(unsigned short)f2bf(p0) | ((unsigned)(unsigned short)f2bf(p1) << 16);
        u.y = (unsigned)(unsigned short)f2bf(p2) | ((unsigned)(unsigned short)f2bf(p3) << 16);
        *(uint2*)&Pb[w][(lc * 4 + r) * 72 + lr * 4] = u;
      }

      // PV: O += P[16][64] * V[64][128]  (k-dim in kv' order on both sides)
      __builtin_amdgcn_s_setprio(1);
#pragma unroll
      for (int kk = 0; kk < 2; ++kk) {
        const s16x8 pf = *(const s16x8*)&Pb[w][lr * 72 + kk * 32 + lc * 8];
#pragma unroll
        for (int db = 0; db < 8; ++db) {
          const s16x8 vf = *(const s16x8*)&Vs[(db * 16 + lr) * 64 + ((kk * 32 + lc * 8) ^ sw)];
          oacc[db] = __builtin_amdgcn_mfma_f32_16x16x32_bf16(pf, vf, oacc[db], 0, 0, 0);
        }
      }
      __builtin_amdgcn_s_setprio(0);
    }

#pragma unroll
    for (int r = 0; r < 4; ++r) {
      const float inv = 1.0f / ssum[r];
      const size_t orow = (size_t)b * 2048 + qbase + lc * 4 + r;
#pragma unroll
      for (int db = 0; db < 8; ++db)
        attn_out[orow * 2048 + h * 128 + db * 16 + lr] = f2bf(oacc[db][r] * inv);
    }
  }
}

// ---------------- launch ----------------

extern "C" void kernel_launch(void* const* d_in, const int* in_sizes, int n_in,
                              void* d_out, int out_size, void* d_ws, size_t ws_size,
                              hipStream_t stream) {
  const float* x    = (const float*)d_in[0];
  const float* cosb = (const float*)d_in[1];
  const float* sinb = (const float*)d_in[2];
  const float* wq   = (const float*)d_in[3];
  const float* wk   = (const float*)d_in[4];
  const float* wv   = (const float*)d_in[5];
  const float* wo   = (const float*)d_in[6];
  float* out = (float*)d_out;

  char* ws = (char*)d_ws;
  short* xb    = (short*)(ws);                 // [4096][2048] bf16 (dead after gemm1)
  short* vtb   = (short*)(ws);                 // reuse: [2][512][2048] bf16 (4MB)
  short* kswzb = (short*)(ws + 4194304);       // reuse: [2][4][2048][128] bf16 (4MB)
  short* wqkvT = (short*)(ws + 16777216);      // [3072][2048] bf16
  short* woT   = (short*)(ws + 29360128);      // [2048][2048] bf16
  short* qkvb  = (short*)(ws + 37748736);      // [4096][3072] bf16
  short* attnb = (short*)(ws + 62914560);      // [4096][2048] bf16

  cvt_f32_bf16<<<8192, 256, 0, stream>>>(x, xb, 8388608);
  transpose_cvt<<<dim3(64, 64), 256, 0, stream>>>(wq, wqkvT, 2048, 2048);
  transpose_cvt<<<dim3(16, 64), 256, 0, stream>>>(wk, wqkvT + 2048 * 2048, 2048, 512);
  transpose_cvt<<<dim3(16, 64), 256, 0, stream>>>(wv, wqkvT + 2560 * 2048, 2048, 512);
  transpose_cvt<<<dim3(64, 64), 256, 0, stream>>>(wo, woT, 2048, 2048);

  gemm_bt<true><<<dim3(32, 24), 256, 0, stream>>>(xb, wqkvT, qkvb, 4096, 3072, 2048);
  rope_kernel<<<20480, 256, 0, stream>>>(qkvb, kswzb, cosb, sinb);
  transpose_v<<<dim3(64, 16, 2), 256, 0, stream>>>(qkvb, vtb);
  flash_attn<<<dim3(16, 16, 2), 256, 0, stream>>>(qkvb, kswzb, vtb, attnb);
  gemm_bt<false><<<dim3(32, 16), 256, 0, stream>>>(attnb, woT, out, 4096, 2048, 2048);
}

// Round 6
// 334.537 us; speedup vs baseline: 1.8754x; 1.1010x over previous
//
#include <hip/hip_runtime.h>

typedef __attribute__((ext_vector_type(4))) float f32x4;
typedef __attribute__((ext_vector_type(8))) short s16x8;

__device__ __forceinline__ float bf2f(short b) {
  unsigned int u = ((unsigned int)(unsigned short)b) << 16;
  return __builtin_bit_cast(float, u);
}
__device__ __forceinline__ short f2bf(float f) {
  unsigned int u = __builtin_bit_cast(unsigned int, f);
  u = (u + 0x7fffu + ((u >> 16) & 1u)) >> 16;
  return (short)u;
}
__device__ __forceinline__ unsigned cvt_pk_bf16(float a, float b) {
  unsigned r;
  asm("v_cvt_pk_bf16_f32 %0, %1, %2" : "=v"(r) : "v"(a), "v"(b));
  return r;
}

__device__ __forceinline__ void async_copy16(void* lds, const void* g) {
  __builtin_amdgcn_global_load_lds((const __attribute__((address_space(1))) unsigned int*)g,
                                   (__attribute__((address_space(3))) unsigned int*)lds,
                                   16, 0, 0);
}

// ---------------- pack kernels ----------------

__global__ __launch_bounds__(256) void cvt_f32_bf16(const float* __restrict__ src,
                                                    short* __restrict__ dst, int n) {
  const int i = (blockIdx.x * 256 + threadIdx.x) * 4;
  if (i >= n) return;
  const float4 v = *(const float4*)&src[i];
  short4 o;
  o.x = f2bf(v.x); o.y = f2bf(v.y); o.z = f2bf(v.z); o.w = f2bf(v.w);
  *(short4*)&dst[i] = o;
}

// src fp32 [R][C] -> dst bf16 [C][R]
__global__ __launch_bounds__(256) void transpose_cvt(const float* __restrict__ src,
                                                     short* __restrict__ dst, int R, int C) {
  __shared__ float t[32][33];
  const int c0 = blockIdx.x * 32, r0 = blockIdx.y * 32;
  const int tx = threadIdx.x & 31;
  const int ty = threadIdx.x >> 5;  // 0..7
#pragma unroll
  for (int i = 0; i < 4; ++i)
    t[ty + 8 * i][tx] = src[(size_t)(r0 + ty + 8 * i) * C + c0 + tx];
  __syncthreads();
#pragma unroll
  for (int i = 0; i < 4; ++i)
    dst[(size_t)(c0 + ty + 8 * i) * R + r0 + tx] = f2bf(t[tx][ty + 8 * i]);
}

// bf16 V slice of qkv [B*2048][3072] -> vt [B][512][2048], kv natural order,
// XOR-swizzled by d (^((d&7)<<3)) within each 64-kv block.
__global__ __launch_bounds__(256) void transpose_v(const short* __restrict__ qkv,
                                                   short* __restrict__ vt) {
  __shared__ short t[32][33];
  const int l0 = blockIdx.x * 32;  // L tile
  const int c0 = blockIdx.y * 32;  // col within 512
  const int b = blockIdx.z;
  const int tx = threadIdx.x & 31, ty = threadIdx.x >> 5;
#pragma unroll
  for (int i = 0; i < 4; ++i)
    t[ty + 8 * i][tx] = qkv[(size_t)(b * 2048 + l0 + ty + 8 * i) * 3072 + 2560 + c0 + tx];
  __syncthreads();
#pragma unroll
  for (int i = 0; i < 4; ++i) {
    const int c = c0 + ty + 8 * i;     // d within 512 (head-aligned: swz uses d&7)
    const int l = l0 + tx;
    const int kvp = (l & 63) ^ ((c & 7) << 3);
    vt[((size_t)b * 512 + c) * 2048 + (l & ~63) + kvp] = t[tx][ty + 8 * i];
  }
}

// ---------------- GEMM: C[M][N] = A[M][K] * BT[N][K]^T ----------------

template <bool OUT_BF16>
__global__ __launch_bounds__(256) void gemm_bt(const short* __restrict__ A,
                                               const short* __restrict__ BT,
                                               void* __restrict__ Cout,
                                               int M, int N, int K) {
  __shared__ short As[128 * 32];
  __shared__ short Bs[128 * 32];
  const int tid = threadIdx.x;
  const int l = tid & 63, wid = tid >> 6;
  const int m0 = blockIdx.x * 128, n0 = blockIdx.y * 128;
  const int wr = (wid >> 1) * 64, wc = (wid & 1) * 64;
  const int lr = l & 15, lc = l >> 4;
  f32x4 acc[4][4] = {};

  for (int k0 = 0; k0 < K; k0 += 32) {
    __syncthreads();
#pragma unroll
    for (int i = 0; i < 2; ++i) {
      const int c = tid + 256 * i;
      const int row = c >> 2, kc = (c & 3) * 8;
      async_copy16((char*)As + (size_t)(i * 256 + wid * 64) * 16,
                   A + (size_t)(m0 + row) * K + k0 + kc);
      async_copy16((char*)Bs + (size_t)(i * 256 + wid * 64) * 16,
                   BT + (size_t)(n0 + row) * K + k0 + kc);
    }
    __syncthreads();
    s16x8 a[4], b[4];
#pragma unroll
    for (int m = 0; m < 4; ++m)
      a[m] = *(const s16x8*)&As[(wr + m * 16 + lr) * 32 + lc * 8];
#pragma unroll
    for (int n = 0; n < 4; ++n)
      b[n] = *(const s16x8*)&Bs[(wc + n * 16 + lr) * 32 + lc * 8];
#pragma unroll
    for (int m = 0; m < 4; ++m)
#pragma unroll
      for (int n = 0; n < 4; ++n)
        acc[m][n] = __builtin_amdgcn_mfma_f32_16x16x32_bf16(a[m], b[n], acc[m][n], 0, 0, 0);
  }

#pragma unroll
  for (int m = 0; m < 4; ++m)
#pragma unroll
    for (int n = 0; n < 4; ++n)
#pragma unroll
      for (int r = 0; r < 4; ++r) {
        const size_t row = (size_t)(m0 + wr + m * 16 + lc * 4 + r);
        const int col = n0 + wc + n * 16 + lr;
        if constexpr (OUT_BF16)
          ((short*)Cout)[row * N + col] = f2bf(acc[m][n][r]);
        else
          ((float*)Cout)[row * N + col] = acc[m][n][r];
      }
}

// ---------------- RoPE ----------------
// Q: in-place on qkv [4096][3072]. K: written to kswz [B][4][2048][128] with
// d-index XOR-swizzled (^((l&7)<<3)) so flash_attn can global_load_lds it linearly.

__global__ __launch_bounds__(256) void rope_kernel(short* __restrict__ qkv,
                                                   short* __restrict__ kswz,
                                                   const float* __restrict__ cosb,
                                                   const float* __restrict__ sinb) {
  const int idx = blockIdx.x * 256 + threadIdx.x;  // 4096*20*64 threads
  const int d = idx & 63;
  const int hh = (idx >> 6) % 20;
  const int row = idx / (64 * 20);
  const int lpos = row & 2047;
  const int col = (hh < 16) ? hh * 128 + d : 2048 + (hh - 16) * 128 + d;
  short* p = qkv + (size_t)row * 3072 + col;
  const float x1 = bf2f(p[0]);
  const float x2 = bf2f(p[64]);
  const float c = cosb[lpos * 128 + d];
  const float sn = sinb[lpos * 128 + d];
  const short o1 = f2bf(x1 * c - x2 * sn);
  const short o2 = f2bf(x2 * c + x1 * sn);
  if (hh < 16) {
    p[0] = o1;
    p[64] = o2;
  } else {
    const int b = row >> 11;
    const int kvh = hh - 16;
    short* kp = kswz + (((size_t)(b * 4 + kvh) * 2048) + lpos) * 128;
    const int sw = (lpos & 7) << 3;
    kp[d ^ sw] = o1;
    kp[(d + 64) ^ sw] = o2;
  }
}

// ---------------- flash attention (causal, GQA 16/4, hd=128) ----------------
// Block = 2 paired q-tiles (qt, 31-qt) of 64 rows -> 33 KV tiles/block, uniform.
// 4 waves x 16 q-rows. KV tile = 64.
// SWAPPED QK^T: sacc = mfma(K, Q) so lane holds S[kv-slots][q=lane&15] --
// row-max is lane-local (15 fmax + 2 shfl), P packs via v_cvt_pk_bf16_f32,
// row-sum accumulated by a ones-column MFMA (auto-rescaled with O).

__global__ __launch_bounds__(256) void flash_attn(const short* __restrict__ qkv,
                                                  const short* __restrict__ kswz,
                                                  const short* __restrict__ vt,
                                                  short* __restrict__ attn_out) {
  __shared__ short Ks[64 * 128];    // [kv][d^((kv&7)<<3)]
  __shared__ short Vs[128 * 64];    // [d][kv^((d&7)<<3)]
  __shared__ uint2 Pb[4][16][16];   // per-wave P: [q][pair^(q&7)], pair=4 slots
  const int tid = threadIdx.x;
  const int l = tid & 63, w = tid >> 6;
  const int lr = l & 15, lc = l >> 4;
  const int sw = (lr & 7) << 3;
  const int qpair = blockIdx.x, h = blockIdx.y, b = blockIdx.z;
  const int kvh = h >> 2;
  const short* Qg = qkv + (size_t)b * 2048 * 3072 + h * 128;
  const short* Kg = kswz + ((size_t)(b * 4 + kvh) * 2048) * 128;
  const short* Vtg = vt + ((size_t)b * 512 + kvh * 128) * 2048;
  const float SCALE2 = 0.12751744166306968f;  // hd^-0.5 * log2(e)
  s16x8 ones;
#pragma unroll
  for (int j = 0; j < 8; ++j) ones[j] = (short)0x3F80;  // bf16 1.0

#pragma unroll 1
  for (int seg = 0; seg < 2; ++seg) {
    const int qt = seg ? (31 - qpair) : qpair;
    const int qbase = qt * 64 + w * 16;

    s16x8 qf[4];
#pragma unroll
    for (int dc = 0; dc < 4; ++dc) {
      qf[dc] = *(const s16x8*)&Qg[(size_t)(qbase + lr) * 3072 + dc * 32 + lc * 8];
#pragma unroll
      for (int j = 0; j < 8; ++j) qf[dc][j] = f2bf(bf2f(qf[dc][j]) * SCALE2);
    }

    f32x4 oacc[8] = {};
    f32x4 osum = {0.f, 0.f, 0.f, 0.f};
    float mrow = -__builtin_inff();
    const int nkt = qt + 1;

    for (int kt = 0; kt < nkt; ++kt) {
      const int kv0 = kt * 64;
      __syncthreads();
      // stage K (16KB) + V (16KB) via async global->LDS, linear dest
#pragma unroll
      for (int i = 0; i < 4; ++i) {
        async_copy16((char*)Ks + i * 4096 + w * 1024,
                     Kg + (size_t)kv0 * 128 + i * 2048 + w * 512 + l * 8);
        async_copy16((char*)Vs + i * 4096 + w * 1024,
                     Vtg + (size_t)(i * 32 + w * 8 + (l >> 3)) * 2048 + kv0 + (l & 7) * 8);
      }
      __syncthreads();

      // swapped QK^T: S^T[kv][q]; lane (lr,lc) holds q=lr, kv slots cb*16+lc*4+r
      f32x4 sacc[4] = {};
      __builtin_amdgcn_s_setprio(1);
#pragma unroll
      for (int cb = 0; cb < 4; ++cb)
#pragma unroll
        for (int dc = 0; dc < 4; ++dc) {
          const s16x8 kf = *(const s16x8*)&Ks[(cb * 16 + lr) * 128 + ((dc * 32 + lc * 8) ^ sw)];
          sacc[cb] = __builtin_amdgcn_mfma_f32_16x16x32_bf16(kf, qf[dc], sacc[cb], 0, 0, 0);
        }
      __builtin_amdgcn_s_setprio(0);

      if (kt == qt) {  // diagonal tile: causal mask (lane-local q)
        const int qrow = qbase + lr;
#pragma unroll
        for (int cb = 0; cb < 4; ++cb)
#pragma unroll
          for (int r = 0; r < 4; ++r)
            if (kv0 + cb * 16 + lc * 4 + r > qrow) sacc[cb][r] = -1e30f;
      }

      // row max: in-lane over 16, then across the 4 lc-groups
      float rm = sacc[0][0];
#pragma unroll
      for (int cb = 0; cb < 4; ++cb)
#pragma unroll
        for (int r = 0; r < 4; ++r)
          if (cb | r) rm = fmaxf(rm, sacc[cb][r]);
      rm = fmaxf(rm, __shfl_xor(rm, 16, 64));
      rm = fmaxf(rm, __shfl_xor(rm, 32, 64));

      if (!__all(rm <= mrow + 8.f)) {  // defer-max (THR=8)
        const float mnew = fmaxf(mrow, rm);
        const float resc = exp2f(mrow - mnew);
        mrow = mnew;
#pragma unroll
        for (int r = 0; r < 4; ++r) {
          // oacc rows live at q=lc*4+r; fetch resc from a lane with lr==lc*4+r
          const float rr = __shfl(resc, (l & 48) | (((l >> 4) & 3) * 4 + r), 64);
          osum[r] *= rr;
#pragma unroll
          for (int db = 0; db < 8; ++db) oacc[db][r] *= rr;
        }
      }

      // P = exp2(S - m), pack to bf16, store natural slot order w/ pair XOR swizzle
#pragma unroll
      for (int cb = 0; cb < 4; ++cb) {
        const float p0 = exp2f(sacc[cb][0] - mrow);
        const float p1 = exp2f(sacc[cb][1] - mrow);
        const float p2 = exp2f(sacc[cb][2] - mrow);
        const float p3 = exp2f(sacc[cb][3] - mrow);
        uint2 u;
        u.x = cvt_pk_bf16(p0, p1);
        u.y = cvt_pk_bf16(p2, p3);
        Pb[w][lr][(4 * cb + lc) ^ (lr & 7)] = u;
      }

      // PV: O += P[16][64] * V[64][128]; ones-column accumulates row sums
      __builtin_amdgcn_s_setprio(1);
#pragma unroll
      for (int kk = 0; kk < 2; ++kk) {
        const uint2 plo = Pb[w][lr][(8 * kk + 2 * lc) ^ (lr & 7)];
        const uint2 phi = Pb[w][lr][(8 * kk + 2 * lc + 1) ^ (lr & 7)];
        union { uint2 u2[2]; s16x8 v; } pu;
        pu.u2[0] = plo; pu.u2[1] = phi;
        const s16x8 pf = pu.v;
#pragma unroll
        for (int db = 0; db < 8; ++db) {
          const s16x8 vf = *(const s16x8*)&Vs[(db * 16 + lr) * 64 + ((kk * 32 + lc * 8) ^ sw)];
          oacc[db] = __builtin_amdgcn_mfma_f32_16x16x32_bf16(pf, vf, oacc[db], 0, 0, 0);
        }
        osum = __builtin_amdgcn_mfma_f32_16x16x32_bf16(pf, ones, osum, 0, 0, 0);
      }
      __builtin_amdgcn_s_setprio(0);
    }

#pragma unroll
    for (int r = 0; r < 4; ++r) {
      const float inv = 1.0f / osum[r];
      const size_t orow = (size_t)b * 2048 + qbase + lc * 4 + r;
#pragma unroll
      for (int db = 0; db < 8; ++db)
        attn_out[orow * 2048 + h * 128 + db * 16 + lr] = f2bf(oacc[db][r] * inv);
    }
  }
}

// ---------------- launch ----------------

extern "C" void kernel_launch(void* const* d_in, const int* in_sizes, int n_in,
                              void* d_out, int out_size, void* d_ws, size_t ws_size,
                              hipStream_t stream) {
  const float* x    = (const float*)d_in[0];
  const float* cosb = (const float*)d_in[1];
  const float* sinb = (const float*)d_in[2];
  const float* wq   = (const float*)d_in[3];
  const float* wk   = (const float*)d_in[4];
  const float* wv   = (const float*)d_in[5];
  const float* wo   = (const float*)d_in[6];
  float* out = (float*)d_out;

  char* ws = (char*)d_ws;
  short* xb    = (short*)(ws);                 // [4096][2048] bf16 (dead after gemm1)
  short* vtb   = (short*)(ws);                 // reuse: [2][512][2048] bf16 (4MB)
  short* kswzb = (short*)(ws + 4194304);       // reuse: [2][4][2048][128] bf16 (4MB)
  short* wqkvT = (short*)(ws + 16777216);      // [3072][2048] bf16
  short* woT   = (short*)(ws + 29360128);      // [2048][2048] bf16
  short* qkvb  = (short*)(ws + 37748736);      // [4096][3072] bf16
  short* attnb = (short*)(ws + 62914560);      // [4096][2048] bf16

  cvt_f32_bf16<<<8192, 256, 0, stream>>>(x, xb, 8388608);
  transpose_cvt<<<dim3(64, 64), 256, 0, stream>>>(wq, wqkvT, 2048, 2048);
  transpose_cvt<<<dim3(16, 64), 256, 0, stream>>>(wk, wqkvT + 2048 * 2048, 2048, 512);
  transpose_cvt<<<dim3(16, 64), 256, 0, stream>>>(wv, wqkvT + 2560 * 2048, 2048, 512);
  transpose_cvt<<<dim3(64, 64), 256, 0, stream>>>(wo, woT, 2048, 2048);

  gemm_bt<true><<<dim3(32, 24), 256, 0, stream>>>(xb, wqkvT, qkvb, 4096, 3072, 2048);
  rope_kernel<<<20480, 256, 0, stream>>>(qkvb, kswzb, cosb, sinb);
  transpose_v<<<dim3(64, 16, 2), 256, 0, stream>>>(qkvb, vtb);
  flash_attn<<<dim3(16, 16, 2), 256, 0, stream>>>(qkvb, kswzb, vtb, attnb);
  gemm_bt<false><<<dim3(32, 16), 256, 0, stream>>>(attnb, woT, out, 4096, 2048, 2048);
}